// Round 17
// baseline (51.670 us; speedup 1.0000x reference)
//
#include <hip/hip_runtime.h>
#include <hip/hip_bf16.h>

#define B_N   256
#define IN_N  1024
#define OUT_N 512
#define P_N   1000
#define NS_N  128

#define K1P   3072   // padded K of GEMM1 (3*P_N)
#define N1P   1024   // padded N of GEMM1
#define K2P   1024   // padded K of GEMM2
#define SK1   16     // split-K GEMM1 (128 blocks)
#define SK2   16     // split-K GEMM2 (64 blocks, 1 K-step each)

typedef __attribute__((ext_vector_type(8))) short short8v;
typedef __attribute__((ext_vector_type(4))) float f32x4;
typedef unsigned short ushort_t;
typedef __attribute__((ext_vector_type(4))) unsigned short ushort4v;

__device__ __forceinline__ float sigmoid_f(float z) { return 1.0f / (1.0f + __expf(-z)); }

__device__ __forceinline__ ushort_t f2bf(float x) {
    return __bfloat16_as_ushort(__float2bfloat16(x));
}
__device__ __forceinline__ float bf2f(ushort_t h) {
    union { unsigned u; float f; } v; v.u = ((unsigned)h) << 16;
    return v.f;
}
__device__ __forceinline__ unsigned pack2(float a, float b) {
    return (unsigned)f2bf(a) | ((unsigned)f2bf(b) << 16);
}
__device__ __forceinline__ f32x4 nt_load4(const float* p) {
    return __builtin_nontemporal_load(reinterpret_cast<const f32x4*>(p));
}

// ---- K1: fused feedback + SDE reduction -> T bf16 [B_N][K1P] (zero-padded) ----
// Block (b, ch): cols [ch*512, ch*512+512). 512 thr = 128 col-groups x 4 time-quarters.
// Each thread reduces 32 steps with non-temporal float4 loads. Exact recombination:
// L = L3 + r32*L2 + r64*L1 + r96*L0; sumE = sum SEq; A = (sumE - retain*L)/(decay*dt).
// T[b,3c+k]: k=0 -> scale*(A-L), k=1 -> scale*A, k=2 -> scale*(A-F); scale = fb*sd/NS.
__global__ __launch_bounds__(512) void sde_fused_kernel(const float* __restrict__ x,
                                                        const float* __restrict__ fb_w,
                                                        const float* __restrict__ fb_b,
                                                        const float* __restrict__ noise,
                                                        const float* __restrict__ decay_param,
                                                        ushort_t* __restrict__ Thi) {
    const int b  = blockIdx.x;
    const int ch = blockIdx.y;
    const int t  = threadIdx.x;
    const int cg = t & 127;       // col group (4 floats)
    const int tq = t >> 7;        // time quarter 0..3

    // feedback dot-product: wave shuffle reduce + one barrier
    float2 xv = ((const float2*)(x + (size_t)b * IN_N))[t];
    float2 wv = ((const float2*)fb_w)[t];
    float partial = xv.x * wv.x + xv.y * wv.y;
    #pragma unroll
    for (int o = 32; o >= 1; o >>= 1) partial += __shfl_down(partial, o, 64);
    __shared__ float wred[8];
    if ((t & 63) == 0) wred[t >> 6] = partial;
    __syncthreads();
    float fbs = wred[0] + wred[1] + wred[2] + wred[3] +
                wred[4] + wred[5] + wred[6] + wred[7];
    float fbv = sigmoid_f(fbs + fb_b[0]);

    float decay = sigmoid_f(decay_param[0]) * 0.5f;
    const float dt = 1.0f / NS_N;
    float retain = 1.0f - decay * dt;
    float inv_omr = 1.0f / (decay * dt);
    float r2 = retain * retain, r4 = r2 * r2, r8 = r4 * r4;
    float r16 = r8 * r8, r32 = r16 * r16;
    float r64 = r32 * r32, r96 = r64 * r32;

    const int c0 = ch * 512 + cg * 4;
    const bool act = (c0 < P_N);          // P_N = 1000, multiple of 4
    const float* base = noise + (size_t)b * NS_N * P_N + (act ? c0 : 0);

    float sE0 = 0.f, sE1 = 0.f, sE2 = 0.f, sE3 = 0.f;
    float L0 = 0.f, L1 = 0.f, L2 = 0.f, L3 = 0.f;
    if (act) {
        const int s0 = tq * 32;
        float rp = 1.0f;                  // retain^{(s0+31)-s}, s descending
        #pragma unroll 8
        for (int ss = s0 + 31; ss >= s0; --ss) {
            f32x4 e = nt_load4(base + (size_t)ss * P_N);
            sE0 += e[0]; sE1 += e[1]; sE2 += e[2]; sE3 += e[3];
            L0 += rp * e[0]; L1 += rp * e[1]; L2 += rp * e[2]; L3 += rp * e[3];
            rp *= retain;
        }
    }

    __shared__ float4 xSE[3][128], xL[3][128], xF[128];
    if (tq < 3) {
        float4 a = {sE0, sE1, sE2, sE3};
        float4 l = {L0, L1, L2, L3};
        xSE[tq][cg] = a; xL[tq][cg] = l;
    }
    if (tq == 0 && act) xF[cg] = *(const float4*)base;   // eps[0]
    __syncthreads();

    if (tq == 3) {
        size_t tb = (size_t)b * K1P + 3 * (size_t)c0;    // byte offset 24*cg, 8B-aligned
        uint2* tp = (uint2*)(Thi + tb);
        if (!act) {
            uint2 z2 = {0u, 0u};
            tp[0] = z2; tp[1] = z2; tp[2] = z2;
            return;
        }
        float4 se0 = xSE[0][cg], se1 = xSE[1][cg], se2 = xSE[2][cg];
        float4 l0 = xL[0][cg], l1 = xL[1][cg], l2 = xL[2][cg], ff = xF[cg];
        float Se[4] = {se0.x + se1.x + se2.x + sE0, se0.y + se1.y + se2.y + sE1,
                       se0.z + se1.z + se2.z + sE2, se0.w + se1.w + se2.w + sE3};
        float Lv[4] = {L0 + r32 * l2.x + r64 * l1.x + r96 * l0.x,
                       L1 + r32 * l2.y + r64 * l1.y + r96 * l0.y,
                       L2 + r32 * l2.z + r64 * l1.z + r96 * l0.z,
                       L3 + r32 * l2.w + r64 * l1.w + r96 * l0.w};
        float Fv[4] = {ff.x, ff.y, ff.z, ff.w};
        float sd = sqrtf(dt);
        float scale = fbv * sd * (1.0f / NS_N);
        float tv[12];
        #pragma unroll
        for (int j = 0; j < 4; ++j) {
            float Aj = (Se[j] - retain * Lv[j]) * inv_omr;
            tv[3 * j + 0] = scale * (Aj - Lv[j]);
            tv[3 * j + 1] = scale * Aj;
            tv[3 * j + 2] = scale * (Aj - Fv[j]);
        }
        uint2 o0 = {pack2(tv[0], tv[1]), pack2(tv[2], tv[3])};
        uint2 o1 = {pack2(tv[4], tv[5]), pack2(tv[6], tv[7])};
        uint2 o2 = {pack2(tv[8], tv[9]), pack2(tv[10], tv[11])};
        tp[0] = o0; tp[1] = o1; tp[2] = o2;
    }
}

// ---- bf16 MFMA NT GEMM, BM=256 (full M), BN=128, BK=64, split-K -> bf16 partials ----
// FLAT 1-D grid, XCD-aware: bid = z + 16*ntile. Same-z blocks (sharing the A K-slice)
// land on one XCD -> A slice L2-hits after first fetch. A staged via global_load_lds
// (pre-swizzled global source, linear LDS dest). B f32 guarded, cvt->bf16 in staging.
// 8 waves as 4x2, wave tile 64x64 = 4x4 frags of 16x16x32.
__global__ __launch_bounds__(512) void gemm_bf16_bm256(const ushort_t* __restrict__ A,
                                                       const float* __restrict__ B,
                                                       ushort_t* __restrict__ Cpart,
                                                       int lda, int ldb,
                                                       int Nvalid, int Kvalid,
                                                       int Kper, int ldc) {
    __shared__ __align__(16) ushort_t As[256 * 64];   // 32 KB
    __shared__ __align__(16) ushort_t Bs[128 * 64];   // 16 KB

    const int tid  = threadIdx.x;
    const int lane = tid & 63;
    const int wave = tid >> 6;
    const int r15  = lane & 15;
    const int g4   = lane >> 4;
    const int wrow = wave >> 1;       // 0..3 -> rows wrow*64
    const int wcol = wave & 1;        // 0..1 -> cols wcol*64
    const int bid  = blockIdx.x;
    const int z    = bid & 15;        // split-K index; z%8 = XCD
    const int n0   = (bid >> 4) * 128;
    const int kbeg = z * Kper;

    f32x4 acc[4][4] = {};

    for (int kt = 0; kt < Kper; kt += 64) {
        const int kk0 = kbeg + kt;
        #pragma unroll
        for (int c = 0; c < 4; ++c) {
            int ci = c * 512 + tid;           // granule slot 0..2047
            int row = ci >> 3;
            int gs  = ci & 7;
            int g   = gs ^ (row & 7);
            const ushort_t* src = A + (size_t)row * lda + kk0 + g * 8;
            __builtin_amdgcn_global_load_lds(
                (const __attribute__((address_space(1))) void*)src,
                (__attribute__((address_space(3))) void*)&As[(size_t)(c * 512 + wave * 64) * 8],
                16, 0, 0);
        }
        #pragma unroll
        for (int c = 0; c < 2; ++c) {
            int chunk = tid + c * 512;
            int row = chunk >> 3, g = chunk & 7;
            int ldsoff = row * 64 + ((g ^ (row & 7)) << 3);
            int k = kk0 + g * 8;
            short8v bh = {0, 0, 0, 0, 0, 0, 0, 0};
            if ((n0 + row) < Nvalid && k < Kvalid) {
                const float* bp = B + (size_t)(n0 + row) * ldb + k;
                float4 b0 = *(const float4*)bp;
                float4 b1 = *(const float4*)(bp + 4);
                bh[0] = (short)f2bf(b0.x); bh[1] = (short)f2bf(b0.y);
                bh[2] = (short)f2bf(b0.z); bh[3] = (short)f2bf(b0.w);
                bh[4] = (short)f2bf(b1.x); bh[5] = (short)f2bf(b1.y);
                bh[6] = (short)f2bf(b1.z); bh[7] = (short)f2bf(b1.w);
            }
            *(short8v*)&Bs[ldsoff] = bh;
        }
        __syncthreads();

        #pragma unroll
        for (int ks = 0; ks < 2; ++ks) {
            const int g = ks * 4 + g4;        // k-granule 0..7
            short8v af[4], bfv[4];
            #pragma unroll
            for (int f = 0; f < 4; ++f) {
                int arow = wrow * 64 + f * 16 + r15;
                af[f] = *(const short8v*)&As[arow * 64 + ((g ^ (arow & 7)) << 3)];
            }
            #pragma unroll
            for (int f = 0; f < 4; ++f) {
                int brow = wcol * 64 + f * 16 + r15;
                bfv[f] = *(const short8v*)&Bs[brow * 64 + ((g ^ (brow & 7)) << 3)];
            }
            #pragma unroll
            for (int mf = 0; mf < 4; ++mf) {
                #pragma unroll
                for (int nf = 0; nf < 4; ++nf) {
                    acc[mf][nf] = __builtin_amdgcn_mfma_f32_16x16x32_bf16(af[mf], bfv[nf], acc[mf][nf], 0, 0, 0);
                }
            }
        }
        __syncthreads();
    }

    // C/D mapping: col = lane&15, row = (lane>>4)*4 + reg  [m89-verified]
    ushort_t* cp = Cpart + (size_t)z * B_N * ldc;
    #pragma unroll
    for (int mf = 0; mf < 4; ++mf) {
        #pragma unroll
        for (int nf = 0; nf < 4; ++nf) {
            #pragma unroll
            for (int r = 0; r < 4; ++r) {
                int m = wrow * 64 + mf * 16 + g4 * 4 + r;
                int n = n0 + wcol * 64 + nf * 16 + r15;
                cp[(size_t)m * ldc + n] = f2bf(acc[mf][nf][r]);
            }
        }
    }
}

// ---- reduce GEMM1 bf16 partials + conv_b -> agg bf16 [B_N][K2P] (zero-padded) ----
__global__ __launch_bounds__(256) void reduce_agg_kernel(const ushort_t* __restrict__ Cpart1,
                                                         const float* __restrict__ conv_b,
                                                         ushort_t* __restrict__ agg) {
    int idx4 = (blockIdx.x * 256 + threadIdx.x) * 4;    // < 256*1024
    int n = idx4 & (N1P - 1);                           // multiple of 4
    float s0 = 0.f, s1 = 0.f, s2 = 0.f, s3 = 0.f;
    if (n < P_N) {
        float4 cb = *(const float4*)(conv_b + n);
        s0 = cb.x; s1 = cb.y; s2 = cb.z; s3 = cb.w;
        #pragma unroll
        for (int z = 0; z < SK1; ++z) {
            ushort4v p = __builtin_nontemporal_load(
                reinterpret_cast<const ushort4v*>(Cpart1 + (size_t)z * (B_N * N1P) + idx4));
            s0 += bf2f(p[0]); s1 += bf2f(p[1]); s2 += bf2f(p[2]); s3 += bf2f(p[3]);
        }
    }
    ushort4v o = {f2bf(s0), f2bf(s1), f2bf(s2), f2bf(s3)};
    *(ushort4v*)(agg + idx4) = o;
}

// ---- reduce GEMM2 bf16 partials + out_b -> final f32 output ----
__global__ __launch_bounds__(256) void reduce_out_kernel(const ushort_t* __restrict__ Cpart2,
                                                         const float* __restrict__ out_b,
                                                         float* __restrict__ out) {
    int idx4 = (blockIdx.x * 256 + threadIdx.x) * 4;    // < 256*512
    int n = idx4 & (OUT_N - 1);
    float4 ob = *(const float4*)(out_b + n);
    float s0 = ob.x, s1 = ob.y, s2 = ob.z, s3 = ob.w;
    #pragma unroll
    for (int z = 0; z < SK2; ++z) {
        ushort4v p = __builtin_nontemporal_load(
            reinterpret_cast<const ushort4v*>(Cpart2 + (size_t)z * (B_N * OUT_N) + idx4));
        s0 += bf2f(p[0]); s1 += bf2f(p[1]); s2 += bf2f(p[2]); s3 += bf2f(p[3]);
    }
    float4 o = {s0, s1, s2, s3};
    *(float4*)(out + idx4) = o;
}

extern "C" void kernel_launch(void* const* d_in, const int* in_sizes, int n_in,
                              void* d_out, int out_size, void* d_ws, size_t ws_size,
                              hipStream_t stream) {
    const float* x           = (const float*)d_in[0];
    const float* noise       = (const float*)d_in[1];
    const float* fb_w        = (const float*)d_in[2];
    const float* fb_b        = (const float*)d_in[3];
    const float* decay_param = (const float*)d_in[4];
    const float* conv_w      = (const float*)d_in[5];  // [P][3P] flat NT layout
    const float* conv_b      = (const float*)d_in[6];
    const float* out_w       = (const float*)d_in[7];  // [OUT, P]
    const float* out_b       = (const float*)d_in[8];
    float* out = (float*)d_out;

    // workspace carve (16B-aligned)
    char* ws = (char*)d_ws;
    size_t off = 0;
    ushort_t* Thi    = (ushort_t*)(ws + off); off += (size_t)B_N * K1P * 2;          // 1.57 MB
    ushort_t* agg    = (ushort_t*)(ws + off); off += (size_t)B_N * K2P * 2;          // 0.52 MB
    ushort_t* Cpart1 = (ushort_t*)(ws + off); off += (size_t)SK1 * B_N * N1P * 2;    // 8.4 MB
    ushort_t* Cpart2 = (ushort_t*)(ws + off); off += (size_t)SK2 * B_N * OUT_N * 2;  // 4.2 MB

    // K1: fused feedback + SDE reduction -> T bf16 [256][3072]
    {
        dim3 grid(B_N, 2);
        sde_fused_kernel<<<grid, 512, 0, stream>>>(x, fb_w, fb_b, noise, decay_param, Thi);
    }

    // K2: GEMM1: Cpart1 = T[256,3072] * conv_w[1000,3000]^T, flat 128-block grid
    gemm_bf16_bm256<<<dim3(N1P / 128 * SK1), 512, 0, stream>>>(Thi, conv_w, Cpart1,
                                                               K1P, 3 * P_N, P_N, 3 * P_N,
                                                               K1P / SK1, N1P);

    // K3: reduce partials + conv_b -> agg bf16 [256][1024]
    reduce_agg_kernel<<<(B_N * N1P) / 1024, 256, 0, stream>>>(Cpart1, conv_b, agg);

    // K4: GEMM2: Cpart2 = agg[256,1024] * out_w[512,1000]^T, flat 64-block grid
    gemm_bf16_bm256<<<dim3(OUT_N / 128 * SK2), 512, 0, stream>>>(agg, out_w, Cpart2,
                                                                 K2P, P_N, OUT_N, P_N,
                                                                 K2P / SK2, OUT_N);

    // K5: reduce GEMM2 partials + out_b -> out
    reduce_out_kernel<<<(B_N * OUT_N) / 1024, 256, 0, stream>>>(Cpart2, out_b, out);
}

// Round 18
// 45.409 us; speedup vs baseline: 1.1379x; 1.1379x over previous
//
#include <hip/hip_runtime.h>
#include <hip/hip_bf16.h>

#define B_N   256
#define IN_N  1024
#define OUT_N 512
#define P_N   1000
#define NS_N  128

#define K1P   3072   // padded K of GEMM1 (3*P_N)
#define N1P   1024   // padded N of GEMM1
#define K2P   1024   // padded K of GEMM2
#define SK1   16     // split-K GEMM1 (128 blocks)
#define SK2   16     // split-K GEMM2 (64 blocks, 1 K-step each)

typedef __attribute__((ext_vector_type(8))) short short8v;
typedef __attribute__((ext_vector_type(4))) float f32x4;
typedef unsigned short ushort_t;
typedef __attribute__((ext_vector_type(4))) unsigned short ushort4v;

__device__ __forceinline__ float sigmoid_f(float z) { return 1.0f / (1.0f + __expf(-z)); }

__device__ __forceinline__ ushort_t f2bf(float x) {
    return __bfloat16_as_ushort(__float2bfloat16(x));
}
__device__ __forceinline__ float bf2f(ushort_t h) {
    union { unsigned u; float f; } v; v.u = ((unsigned)h) << 16;
    return v.f;
}
__device__ __forceinline__ unsigned pack2(float a, float b) {
    return (unsigned)f2bf(a) | ((unsigned)f2bf(b) << 16);
}

// ---- K1: fused feedback + SDE reduction -> T bf16 [B_N][K1P] (zero-padded) ----
// Block (b, ch): cols [ch*512, ch*512+512). 512 thr = 128 col-groups x 4 time-quarters.
// Each thread reduces 32 steps with float4 loads. Exact recombination:
// L = L3 + r32*L2 + r64*L1 + r96*L0; sumE = sum SEq; A = (sumE - retain*L)/(decay*dt).
// T[b,3c+k]: k=0 -> scale*(A-L), k=1 -> scale*A, k=2 -> scale*(A-F); scale = fb*sd/NS.
__global__ __launch_bounds__(512) void sde_fused_kernel(const float* __restrict__ x,
                                                        const float* __restrict__ fb_w,
                                                        const float* __restrict__ fb_b,
                                                        const float* __restrict__ noise,
                                                        const float* __restrict__ decay_param,
                                                        ushort_t* __restrict__ Thi) {
    const int b  = blockIdx.x;
    const int ch = blockIdx.y;
    const int t  = threadIdx.x;
    const int cg = t & 127;       // col group (4 floats)
    const int tq = t >> 7;        // time quarter 0..3

    // feedback dot-product: wave shuffle reduce + one barrier
    float2 xv = ((const float2*)(x + (size_t)b * IN_N))[t];
    float2 wv = ((const float2*)fb_w)[t];
    float partial = xv.x * wv.x + xv.y * wv.y;
    #pragma unroll
    for (int o = 32; o >= 1; o >>= 1) partial += __shfl_down(partial, o, 64);
    __shared__ float wred[8];
    if ((t & 63) == 0) wred[t >> 6] = partial;
    __syncthreads();
    float fbs = wred[0] + wred[1] + wred[2] + wred[3] +
                wred[4] + wred[5] + wred[6] + wred[7];
    float fbv = sigmoid_f(fbs + fb_b[0]);

    float decay = sigmoid_f(decay_param[0]) * 0.5f;
    const float dt = 1.0f / NS_N;
    float retain = 1.0f - decay * dt;
    float inv_omr = 1.0f / (decay * dt);
    float r2 = retain * retain, r4 = r2 * r2, r8 = r4 * r4;
    float r16 = r8 * r8, r32 = r16 * r16;
    float r64 = r32 * r32, r96 = r64 * r32;

    const int c0 = ch * 512 + cg * 4;
    const bool act = (c0 < P_N);          // P_N = 1000, multiple of 4
    const float* base = noise + (size_t)b * NS_N * P_N + (act ? c0 : 0);

    float4 sE = {0, 0, 0, 0}, L = {0, 0, 0, 0};
    if (act) {
        const int s0 = tq * 32;
        float rp = 1.0f;                  // retain^{(s0+31)-s}, s descending
        #pragma unroll 8
        for (int ss = s0 + 31; ss >= s0; --ss) {
            float4 e = *(const float4*)(base + (size_t)ss * P_N);
            sE.x += e.x; sE.y += e.y; sE.z += e.z; sE.w += e.w;
            L.x += rp * e.x; L.y += rp * e.y; L.z += rp * e.z; L.w += rp * e.w;
            rp *= retain;
        }
    }

    __shared__ float4 xSE[3][128], xL[3][128], xF[128];
    if (tq < 3) { xSE[tq][cg] = sE; xL[tq][cg] = L; }
    if (tq == 0 && act) xF[cg] = *(const float4*)base;   // eps[0] (L1-hot)
    __syncthreads();

    if (tq == 3) {
        size_t tb = (size_t)b * K1P + 3 * (size_t)c0;    // byte offset 24*cg, 8B-aligned
        uint2* tp = (uint2*)(Thi + tb);
        if (!act) {
            uint2 z2 = {0u, 0u};
            tp[0] = z2; tp[1] = z2; tp[2] = z2;
            return;
        }
        float4 se0 = xSE[0][cg], se1 = xSE[1][cg], se2 = xSE[2][cg];
        float4 l0 = xL[0][cg], l1 = xL[1][cg], l2 = xL[2][cg], ff = xF[cg];
        float Se[4] = {se0.x + se1.x + se2.x + sE.x, se0.y + se1.y + se2.y + sE.y,
                       se0.z + se1.z + se2.z + sE.z, se0.w + se1.w + se2.w + sE.w};
        float Lv[4] = {L.x + r32 * l2.x + r64 * l1.x + r96 * l0.x,
                       L.y + r32 * l2.y + r64 * l1.y + r96 * l0.y,
                       L.z + r32 * l2.z + r64 * l1.z + r96 * l0.z,
                       L.w + r32 * l2.w + r64 * l1.w + r96 * l0.w};
        float Fv[4] = {ff.x, ff.y, ff.z, ff.w};
        float sd = sqrtf(dt);
        float scale = fbv * sd * (1.0f / NS_N);
        float tv[12];
        #pragma unroll
        for (int j = 0; j < 4; ++j) {
            float Aj = (Se[j] - retain * Lv[j]) * inv_omr;
            tv[3 * j + 0] = scale * (Aj - Lv[j]);
            tv[3 * j + 1] = scale * Aj;
            tv[3 * j + 2] = scale * (Aj - Fv[j]);
        }
        uint2 o0 = {pack2(tv[0], tv[1]), pack2(tv[2], tv[3])};
        uint2 o1 = {pack2(tv[4], tv[5]), pack2(tv[6], tv[7])};
        uint2 o2 = {pack2(tv[8], tv[9]), pack2(tv[10], tv[11])};
        tp[0] = o0; tp[1] = o1; tp[2] = o2;
    }
}

// ---- bf16 MFMA NT GEMM, BM=256 (full M), BN=128, BK=64, split-K -> bf16 partials ----
// FLAT 1-D grid, XCD-aware: bid = z + 16*ntile. Same-z blocks (which share the A
// K-slice) have bid ≡ z (mod 16) -> same bid%8 -> same XCD -> A slice L2-hits after
// first fetch. A staged via global_load_lds (pre-swizzled global source, linear LDS
// dest). B f32 guarded, cvt->bf16 during staging. 8 waves as 4x2, wave tile 64x64.
__global__ __launch_bounds__(512) void gemm_bf16_bm256(const ushort_t* __restrict__ A,
                                                       const float* __restrict__ B,
                                                       ushort_t* __restrict__ Cpart,
                                                       int lda, int ldb,
                                                       int Nvalid, int Kvalid,
                                                       int Kper, int ldc) {
    __shared__ __align__(16) ushort_t As[256 * 64];   // 32 KB
    __shared__ __align__(16) ushort_t Bs[128 * 64];   // 16 KB

    const int tid  = threadIdx.x;
    const int lane = tid & 63;
    const int wave = tid >> 6;
    const int r15  = lane & 15;
    const int g4   = lane >> 4;
    const int wrow = wave >> 1;       // 0..3 -> rows wrow*64
    const int wcol = wave & 1;        // 0..1 -> cols wcol*64
    const int bid  = blockIdx.x;
    const int z    = bid & 15;        // split-K index; z%8 = bid%8 = XCD
    const int n0   = (bid >> 4) * 128;
    const int kbeg = z * Kper;

    f32x4 acc[4][4] = {};

    for (int kt = 0; kt < Kper; kt += 64) {
        const int kk0 = kbeg + kt;
        // stage A: 256 rows x 8 granules = 2048 chunks, 4/thread, direct-to-LDS.
        #pragma unroll
        for (int c = 0; c < 4; ++c) {
            int ci = c * 512 + tid;           // granule slot 0..2047
            int row = ci >> 3;
            int gs  = ci & 7;
            int g   = gs ^ (row & 7);
            const ushort_t* src = A + (size_t)row * lda + kk0 + g * 8;
            __builtin_amdgcn_global_load_lds(
                (const __attribute__((address_space(1))) void*)src,
                (__attribute__((address_space(3))) void*)&As[(size_t)(c * 512 + wave * 64) * 8],
                16, 0, 0);
        }
        // stage B: 128 rows x 8 granules = 1024 chunks, 2/thread, cvt f32->bf16
        #pragma unroll
        for (int c = 0; c < 2; ++c) {
            int chunk = tid + c * 512;
            int row = chunk >> 3, g = chunk & 7;
            int ldsoff = row * 64 + ((g ^ (row & 7)) << 3);
            int k = kk0 + g * 8;
            short8v bh = {0, 0, 0, 0, 0, 0, 0, 0};
            if ((n0 + row) < Nvalid && k < Kvalid) {
                const float* bp = B + (size_t)(n0 + row) * ldb + k;
                float4 b0 = *(const float4*)bp;
                float4 b1 = *(const float4*)(bp + 4);
                bh[0] = (short)f2bf(b0.x); bh[1] = (short)f2bf(b0.y);
                bh[2] = (short)f2bf(b0.z); bh[3] = (short)f2bf(b0.w);
                bh[4] = (short)f2bf(b1.x); bh[5] = (short)f2bf(b1.y);
                bh[6] = (short)f2bf(b1.z); bh[7] = (short)f2bf(b1.w);
            }
            *(short8v*)&Bs[ldsoff] = bh;
        }
        __syncthreads();

        #pragma unroll
        for (int ks = 0; ks < 2; ++ks) {
            const int g = ks * 4 + g4;        // k-granule 0..7
            short8v af[4], bfv[4];
            #pragma unroll
            for (int f = 0; f < 4; ++f) {
                int arow = wrow * 64 + f * 16 + r15;
                af[f] = *(const short8v*)&As[arow * 64 + ((g ^ (arow & 7)) << 3)];
            }
            #pragma unroll
            for (int f = 0; f < 4; ++f) {
                int brow = wcol * 64 + f * 16 + r15;
                bfv[f] = *(const short8v*)&Bs[brow * 64 + ((g ^ (brow & 7)) << 3)];
            }
            #pragma unroll
            for (int mf = 0; mf < 4; ++mf) {
                #pragma unroll
                for (int nf = 0; nf < 4; ++nf) {
                    acc[mf][nf] = __builtin_amdgcn_mfma_f32_16x16x32_bf16(af[mf], bfv[nf], acc[mf][nf], 0, 0, 0);
                }
            }
        }
        __syncthreads();
    }

    // C/D mapping: col = lane&15, row = (lane>>4)*4 + reg  [m89-verified]
    ushort_t* cp = Cpart + (size_t)z * B_N * ldc;
    #pragma unroll
    for (int mf = 0; mf < 4; ++mf) {
        #pragma unroll
        for (int nf = 0; nf < 4; ++nf) {
            #pragma unroll
            for (int r = 0; r < 4; ++r) {
                int m = wrow * 64 + mf * 16 + g4 * 4 + r;
                int n = n0 + wcol * 64 + nf * 16 + r15;
                cp[(size_t)m * ldc + n] = f2bf(acc[mf][nf][r]);
            }
        }
    }
}

// ---- reduce GEMM1 bf16 partials + conv_b -> agg bf16 [B_N][K2P] (zero-padded) ----
__global__ __launch_bounds__(256) void reduce_agg_kernel(const ushort_t* __restrict__ Cpart1,
                                                         const float* __restrict__ conv_b,
                                                         ushort_t* __restrict__ agg) {
    int idx4 = (blockIdx.x * 256 + threadIdx.x) * 4;    // < 256*1024
    int n = idx4 & (N1P - 1);                           // multiple of 4
    float s0 = 0.f, s1 = 0.f, s2 = 0.f, s3 = 0.f;
    if (n < P_N) {
        float4 cb = *(const float4*)(conv_b + n);
        s0 = cb.x; s1 = cb.y; s2 = cb.z; s3 = cb.w;
        #pragma unroll
        for (int z = 0; z < SK1; ++z) {
            ushort4v p = *(const ushort4v*)(Cpart1 + (size_t)z * (B_N * N1P) + idx4);
            s0 += bf2f(p[0]); s1 += bf2f(p[1]); s2 += bf2f(p[2]); s3 += bf2f(p[3]);
        }
    }
    ushort4v o = {f2bf(s0), f2bf(s1), f2bf(s2), f2bf(s3)};
    *(ushort4v*)(agg + idx4) = o;
}

// ---- reduce GEMM2 bf16 partials + out_b -> final f32 output ----
__global__ __launch_bounds__(256) void reduce_out_kernel(const ushort_t* __restrict__ Cpart2,
                                                         const float* __restrict__ out_b,
                                                         float* __restrict__ out) {
    int idx4 = (blockIdx.x * 256 + threadIdx.x) * 4;    // < 256*512
    int n = idx4 & (OUT_N - 1);
    float4 ob = *(const float4*)(out_b + n);
    float s0 = ob.x, s1 = ob.y, s2 = ob.z, s3 = ob.w;
    #pragma unroll
    for (int z = 0; z < SK2; ++z) {
        ushort4v p = *(const ushort4v*)(Cpart2 + (size_t)z * (B_N * OUT_N) + idx4);
        s0 += bf2f(p[0]); s1 += bf2f(p[1]); s2 += bf2f(p[2]); s3 += bf2f(p[3]);
    }
    float4 o = {s0, s1, s2, s3};
    *(float4*)(out + idx4) = o;
}

extern "C" void kernel_launch(void* const* d_in, const int* in_sizes, int n_in,
                              void* d_out, int out_size, void* d_ws, size_t ws_size,
                              hipStream_t stream) {
    const float* x           = (const float*)d_in[0];
    const float* noise       = (const float*)d_in[1];
    const float* fb_w        = (const float*)d_in[2];
    const float* fb_b        = (const float*)d_in[3];
    const float* decay_param = (const float*)d_in[4];
    const float* conv_w      = (const float*)d_in[5];  // [P][3P] flat NT layout
    const float* conv_b      = (const float*)d_in[6];
    const float* out_w       = (const float*)d_in[7];  // [OUT, P]
    const float* out_b       = (const float*)d_in[8];
    float* out = (float*)d_out;

    // workspace carve (16B-aligned)
    char* ws = (char*)d_ws;
    size_t off = 0;
    ushort_t* Thi    = (ushort_t*)(ws + off); off += (size_t)B_N * K1P * 2;          // 1.57 MB
    ushort_t* agg    = (ushort_t*)(ws + off); off += (size_t)B_N * K2P * 2;          // 0.52 MB
    ushort_t* Cpart1 = (ushort_t*)(ws + off); off += (size_t)SK1 * B_N * N1P * 2;    // 8.4 MB
    ushort_t* Cpart2 = (ushort_t*)(ws + off); off += (size_t)SK2 * B_N * OUT_N * 2;  // 4.2 MB

    // K1: fused feedback + SDE reduction -> T bf16 [256][3072]
    {
        dim3 grid(B_N, 2);
        sde_fused_kernel<<<grid, 512, 0, stream>>>(x, fb_w, fb_b, noise, decay_param, Thi);
    }

    // K2: GEMM1: Cpart1 = T[256,3072] * conv_w[1000,3000]^T, flat 128-block grid,
    //     z = bid&15 (same-z -> same XCD -> shared A K-slice L2-hits)
    gemm_bf16_bm256<<<dim3(N1P / 128 * SK1), 512, 0, stream>>>(Thi, conv_w, Cpart1,
                                                               K1P, 3 * P_N, P_N, 3 * P_N,
                                                               K1P / SK1, N1P);

    // K3: reduce partials + conv_b -> agg bf16 [256][1024]
    reduce_agg_kernel<<<(B_N * N1P) / 1024, 256, 0, stream>>>(Cpart1, conv_b, agg);

    // K4: GEMM2: Cpart2 = agg[256,1024] * out_w[512,1000]^T, flat 64-block grid
    gemm_bf16_bm256<<<dim3(OUT_N / 128 * SK2), 512, 0, stream>>>(agg, out_w, Cpart2,
                                                                 K2P, P_N, OUT_N, P_N,
                                                                 K2P / SK2, OUT_N);

    // K5: reduce GEMM2 partials + out_b -> out
    reduce_out_kernel<<<(B_N * OUT_N) / 1024, 256, 0, stream>>>(Cpart2, out_b, out);
}